// Round 4
// baseline (217.354 us; speedup 1.0000x reference)
//
#include <hip/hip_runtime.h>
#include <hip/hip_bf16.h>
#include <cstdint>
#include <cstddef>

// Problem constants (from reference)
#define F0v   2048
#define F1v   2304
#define F2v   2560
#define E1v   256
#define E2v   256
#define BROWS 8192
#define ODIM  1024
#define NNZv  262144
#define NBv   1024

typedef __bf16 bf16x8 __attribute__((ext_vector_type(8)));
typedef float floatx4 __attribute__((ext_vector_type(4)));

__device__ __forceinline__ unsigned short f2bf(float f) {
  unsigned int u = __float_as_uint(f);
  u += 0x7FFFu + ((u >> 16) & 1u);   // round-to-nearest-even
  return (unsigned short)(u >> 16);
}

__device__ __forceinline__ void async_ld16(const void* g, void* l) {
  __builtin_amdgcn_global_load_lds(
      (const __attribute__((address_space(1))) unsigned int*)g,
      (__attribute__((address_space(3))) unsigned int*)l, 16, 0, 0);
}

// ---------------------------------------------------------------------------
// Kernel 1 (fused): blocks [0,8192) build h rows (ONE barrier, closed-form
// two-hop tails); blocks [8192,9216) do the COO scatter-add.
// Tail col j == relu(relu(x[src]*wa)*wb); wb=1 encodes single-hop exactly.
// ---------------------------------------------------------------------------
__global__ __launch_bounds__(256) void fused_pre_kernel(
    const float* __restrict__ x, const float* __restrict__ e1w,
    const float* __restrict__ e2w, const int* __restrict__ e1p,
    const int* __restrict__ e2p, unsigned short* __restrict__ h,
    const int* __restrict__ wr, const int* __restrict__ wc,
    const float* __restrict__ wv, const int* __restrict__ bidx,
    const float* __restrict__ bv, float* __restrict__ Wd,
    float* __restrict__ bias) {
  __shared__ float xrow[F0v];
  __shared__ int   tsrc[E1v + E2v];
  __shared__ float twa[E1v + E2v];
  __shared__ float twb[E1v + E2v];
  const int tid = threadIdx.x;

  if (blockIdx.x >= BROWS) {
    // ---- scatter branch ----
    int gid = (blockIdx.x - BROWS) * 256 + tid;
    if (gid < NNZv)
      atomicAdd(&Wd[(size_t)wr[gid] * F2v + wc[gid]], wv[gid]);
    if (gid < NBv)
      atomicAdd(&bias[bidx[gid]], bv[gid]);
    return;
  }

  // ---- build_h branch ----
  const int b = blockIdx.x;
  const float* xr = x + (size_t)b * F0v;
  unsigned short* hr = h + (size_t)b * F2v;

  // tail-resolution table (identical per block; cheap recompute)
  {
    tsrc[tid] = e1p[tid]; twa[tid] = e1w[tid]; twb[tid] = 1.0f;
    int p2 = e2p[tid]; float w2 = e2w[tid];
    if (p2 < F0v) {
      tsrc[E1v + tid] = p2;  twa[E1v + tid] = w2;  twb[E1v + tid] = 1.0f;
    } else {
      int q = p2 - F0v;
      tsrc[E1v + tid] = e1p[q]; twa[E1v + tid] = e1w[q]; twb[E1v + tid] = w2;
    }
  }

  float4 v0 = ((const float4*)xr)[tid * 2];
  float4 v1 = ((const float4*)xr)[tid * 2 + 1];
  ((float4*)xrow)[tid * 2] = v0;
  ((float4*)xrow)[tid * 2 + 1] = v1;
  union { unsigned short us[8]; uint4 u4; } pk;
  pk.us[0] = f2bf(v0.x); pk.us[1] = f2bf(v0.y);
  pk.us[2] = f2bf(v0.z); pk.us[3] = f2bf(v0.w);
  pk.us[4] = f2bf(v1.x); pk.us[5] = f2bf(v1.y);
  pk.us[6] = f2bf(v1.z); pk.us[7] = f2bf(v1.w);
  ((uint4*)hr)[tid] = pk.u4;   // cols tid*8 .. tid*8+7
  __syncthreads();

  // two tail cols per thread: 2048+2*tid, 2049+2*tid
  int j0 = tid * 2;
  float a0 = fmaxf(fmaxf(xrow[tsrc[j0]] * twa[j0], 0.0f) * twb[j0], 0.0f);
  float a1 = fmaxf(fmaxf(xrow[tsrc[j0 + 1]] * twa[j0 + 1], 0.0f) * twb[j0 + 1], 0.0f);
  unsigned int packed = (unsigned int)f2bf(a0) | ((unsigned int)f2bf(a1) << 16);
  ((unsigned int*)(hr + F0v))[tid] = packed;
}

// ---------------------------------------------------------------------------
// Kernel 2: W f32 -> bf16 (8 elems/thread)
// ---------------------------------------------------------------------------
__global__ __launch_bounds__(256) void convert_kernel(
    const float* __restrict__ Wd, unsigned short* __restrict__ Wb) {
  int gid = blockIdx.x * 256 + threadIdx.x;  // 0 .. 327679
  const float4* src = (const float4*)Wd;
  float4 a = src[gid * 2];
  float4 b = src[gid * 2 + 1];
  union { unsigned short us[8]; uint4 u4; } pk;
  pk.us[0] = f2bf(a.x); pk.us[1] = f2bf(a.y);
  pk.us[2] = f2bf(a.z); pk.us[3] = f2bf(a.w);
  pk.us[4] = f2bf(b.x); pk.us[5] = f2bf(b.y);
  pk.us[6] = f2bf(b.z); pk.us[7] = f2bf(b.w);
  ((uint4*)Wb)[gid] = pk.u4;
}

// ---------------------------------------------------------------------------
// Kernel 3: C = h @ W^T + bias.  128x64 tile, BK=32, double-buffered LDS
// (24 KB/block -> up to 6 blocks/CU; grid 1024 -> 4/CU avg for stall
// interleaving), 256 threads (4 waves), wave-tile 64x32 = acc[4][2].
// BK=32 swizzle: 16B seg s stored for global seg (s-(row>>1))&3 -> exact
// 2-way bank aliasing (free, m136), coalescing unchanged.
// ---------------------------------------------------------------------------
#define BM 128
#define BN 64
#define BK 32

__global__ __launch_bounds__(256, 6) void gemm_bt_kernel(
    const unsigned short* __restrict__ A,
    const unsigned short* __restrict__ Bw,
    const float* __restrict__ bias,
    float* __restrict__ C) {
  __shared__ unsigned short As[2][BM * BK];   // 2 x 8 KB
  __shared__ unsigned short Bs[2][BN * BK];   // 2 x 4 KB
  const int tid = threadIdx.x;
  const int wave = tid >> 6;      // 0..3
  const int lane = tid & 63;

  // XCD swizzle: grid (16, 64), id%8 = XCD. XCD k owns M-tiles [8k,8k+8)
  // across all 16 N-tiles: per-XCD unique A ~5MB + shared W ~5MB.
  const int id = blockIdx.y * 16 + blockIdx.x;
  const int ty = (id & 7) * 8 + ((id >> 3) & 7);   // M-tile 0..63
  const int tx = id >> 6;                          // N-tile 0..15
  const int m0 = ty * BM;
  const int n0 = tx * BN;
  const int wm = wave >> 1;       // 0..1  (64-row half of M)
  const int wn = wave & 1;        // 0..1  (32-col half of N)
  const int quad = lane >> 4;     // 0..3
  const int r16 = lane & 15;

  // Staging: chunk = 16 rows x 32 cols (1 KiB). A = 8 chunks (2/wave),
  // B = 4 chunks (1/wave). Lane L: row L/4, stored seg L%4, sourcing
  // global seg (L%4 - (row>>1)) & 3   [the swizzle].
  const int lr = lane >> 2;                       // 0..15 row in chunk
  const int ls = lane & 3;                        // stored 16B seg
  const int gs = (ls - (lr >> 1)) & 3;            // global 16B seg
  const unsigned short* gA0 = A + (size_t)(m0 + wave * 32 + lr) * F2v + gs * 8;
  const unsigned short* gA1 = A + (size_t)(m0 + wave * 32 + 16 + lr) * F2v + gs * 8;
  const unsigned short* gB0 = Bw + (size_t)(n0 + wave * 16 + lr) * F2v + gs * 8;
  const int lA0 = wave * 1024, lA1 = wave * 1024 + 512, lB0 = wave * 512;

  floatx4 acc[4][2];
  floatx4 zz = {0.f, 0.f, 0.f, 0.f};
#pragma unroll
  for (int i = 0; i < 4; ++i)
#pragma unroll
    for (int j = 0; j < 2; ++j) acc[i][j] = zz;

  // prologue: stage k-block 0 into buffer 0
  async_ld16(gA0, &As[0][lA0]);
  async_ld16(gA1, &As[0][lA1]);
  async_ld16(gB0, &Bs[0][lB0]);

  // fragment seg (uniform across mi/ni since 8|16-row steps): (quad+(r16>>1))&3
  const int fseg = ((quad + (r16 >> 1)) & 3) * 8;

  for (int k0 = 0; k0 < F2v; k0 += BK) {
    const int pb = (k0 >> 5) & 1;
    __syncthreads();   // drains this buffer's loads; frees other buffer
    if (k0 + BK < F2v) {
      const int nb = pb ^ 1;
      async_ld16(gA0 + k0 + BK, &As[nb][lA0]);
      async_ld16(gA1 + k0 + BK, &As[nb][lA1]);
      async_ld16(gB0 + k0 + BK, &Bs[nb][lB0]);
    }

    bf16x8 af[4], bfr[2];
#pragma unroll
    for (int mi = 0; mi < 4; ++mi) {
      int row = wm * 64 + mi * 16 + r16;
      af[mi] = *(const bf16x8*)&As[pb][row * BK + fseg];
    }
#pragma unroll
    for (int ni = 0; ni < 2; ++ni) {
      int row = wn * 32 + ni * 16 + r16;
      bfr[ni] = *(const bf16x8*)&Bs[pb][row * BK + fseg];
    }
#pragma unroll
    for (int mi = 0; mi < 4; ++mi)
#pragma unroll
      for (int ni = 0; ni < 2; ++ni)
        acc[mi][ni] = __builtin_amdgcn_mfma_f32_16x16x32_bf16(
            af[mi], bfr[ni], acc[mi][ni], 0, 0, 0);
  }

  // Epilogue: C/D layout col = lane&15, row = quad*4 + reg (m89/m91 verified)
#pragma unroll
  for (int ni = 0; ni < 2; ++ni) {
    int col = n0 + wn * 32 + ni * 16 + r16;
    float bc = bias[col];
#pragma unroll
    for (int mi = 0; mi < 4; ++mi) {
      int row = m0 + wm * 64 + mi * 16 + quad * 4;
#pragma unroll
      for (int rg = 0; rg < 4; ++rg)
        C[(size_t)(row + rg) * ODIM + col] = acc[mi][ni][rg] + bc;
    }
  }
}

// ---------------------------------------------------------------------------
extern "C" void kernel_launch(void* const* d_in, const int* in_sizes, int n_in,
                              void* d_out, int out_size, void* d_ws, size_t ws_size,
                              hipStream_t stream) {
  const float* x    = (const float*)d_in[0];
  const float* e1w  = (const float*)d_in[1];
  const float* e2w  = (const float*)d_in[2];
  const float* wv   = (const float*)d_in[3];
  const float* bv   = (const float*)d_in[4];
  const int*   e1p  = (const int*)d_in[5];
  const int*   e2p  = (const int*)d_in[6];
  const int*   wr   = (const int*)d_in[7];
  const int*   wc   = (const int*)d_in[8];
  const int*   bidx = (const int*)d_in[9];
  float* out = (float*)d_out;

  // Workspace carve (total ~57.7 MB)
  char* ws = (char*)d_ws;
  const size_t h_bytes  = (size_t)BROWS * F2v * 2;        // 41,943,040
  const size_t wd_bytes = (size_t)ODIM * F2v * 4;         // 10,485,760
  const size_t b_bytes  = (size_t)ODIM * 4;               // 4,096
  unsigned short* h   = (unsigned short*)ws;
  float* Wd           = (float*)(ws + h_bytes);
  float* bias         = (float*)(ws + h_bytes + wd_bytes);
  unsigned short* Wb  = (unsigned short*)(ws + h_bytes + wd_bytes + b_bytes);

  hipMemsetAsync(Wd, 0, wd_bytes + b_bytes, stream);
  fused_pre_kernel<<<BROWS + NNZv / 256, 256, 0, stream>>>(
      x, e1w, e2w, e1p, e2p, h, wr, wc, wv, bidx, bv, Wd, bias);
  convert_kernel<<<(ODIM * F2v / 8) / 256, 256, 0, stream>>>(Wd, Wb);
  gemm_bt_kernel<<<dim3(ODIM / BN, BROWS / BM), 256, 0, stream>>>(h, Wb, bias, out);
}

// Round 5
// 190.790 us; speedup vs baseline: 1.1392x; 1.1392x over previous
//
#include <hip/hip_runtime.h>
#include <hip/hip_bf16.h>
#include <cstdint>
#include <cstddef>

// Problem constants (from reference)
#define F0v   2048
#define F1v   2304
#define F2v   2560
#define E1v   256
#define E2v   256
#define BROWS 8192
#define ODIM  1024
#define NNZv  262144
#define NBv   1024

typedef __bf16 bf16x8 __attribute__((ext_vector_type(8)));
typedef float floatx16 __attribute__((ext_vector_type(16)));

__device__ __forceinline__ unsigned short f2bf(float f) {
  unsigned int u = __float_as_uint(f);
  u += 0x7FFFu + ((u >> 16) & 1u);   // round-to-nearest-even
  return (unsigned short)(u >> 16);
}

__device__ __forceinline__ void async_ld16(const void* g, void* l) {
  __builtin_amdgcn_global_load_lds(
      (const __attribute__((address_space(1))) unsigned int*)g,
      (__attribute__((address_space(3))) unsigned int*)l, 16, 0, 0);
}

// ---------------------------------------------------------------------------
// Kernel 1 (fused): blocks [0,8192) build h rows (one barrier, closed-form
// two-hop tails); blocks [8192,9216) do the COO scatter-add.
// ---------------------------------------------------------------------------
__global__ __launch_bounds__(256) void fused_pre_kernel(
    const float* __restrict__ x, const float* __restrict__ e1w,
    const float* __restrict__ e2w, const int* __restrict__ e1p,
    const int* __restrict__ e2p, unsigned short* __restrict__ h,
    const int* __restrict__ wr, const int* __restrict__ wc,
    const float* __restrict__ wv, const int* __restrict__ bidx,
    const float* __restrict__ bv, float* __restrict__ Wd,
    float* __restrict__ bias) {
  __shared__ float xrow[F0v];
  __shared__ int   tsrc[E1v + E2v];
  __shared__ float twa[E1v + E2v];
  __shared__ float twb[E1v + E2v];
  const int tid = threadIdx.x;

  if (blockIdx.x >= BROWS) {
    int gid = (blockIdx.x - BROWS) * 256 + tid;
    if (gid < NNZv)
      atomicAdd(&Wd[(size_t)wr[gid] * F2v + wc[gid]], wv[gid]);
    if (gid < NBv)
      atomicAdd(&bias[bidx[gid]], bv[gid]);
    return;
  }

  const int b = blockIdx.x;
  const float* xr = x + (size_t)b * F0v;
  unsigned short* hr = h + (size_t)b * F2v;

  {
    tsrc[tid] = e1p[tid]; twa[tid] = e1w[tid]; twb[tid] = 1.0f;
    int p2 = e2p[tid]; float w2 = e2w[tid];
    if (p2 < F0v) {
      tsrc[E1v + tid] = p2;  twa[E1v + tid] = w2;  twb[E1v + tid] = 1.0f;
    } else {
      int q = p2 - F0v;
      tsrc[E1v + tid] = e1p[q]; twa[E1v + tid] = e1w[q]; twb[E1v + tid] = w2;
    }
  }

  float4 v0 = ((const float4*)xr)[tid * 2];
  float4 v1 = ((const float4*)xr)[tid * 2 + 1];
  ((float4*)xrow)[tid * 2] = v0;
  ((float4*)xrow)[tid * 2 + 1] = v1;
  union { unsigned short us[8]; uint4 u4; } pk;
  pk.us[0] = f2bf(v0.x); pk.us[1] = f2bf(v0.y);
  pk.us[2] = f2bf(v0.z); pk.us[3] = f2bf(v0.w);
  pk.us[4] = f2bf(v1.x); pk.us[5] = f2bf(v1.y);
  pk.us[6] = f2bf(v1.z); pk.us[7] = f2bf(v1.w);
  ((uint4*)hr)[tid] = pk.u4;
  __syncthreads();

  int j0 = tid * 2;
  float a0 = fmaxf(fmaxf(xrow[tsrc[j0]] * twa[j0], 0.0f) * twb[j0], 0.0f);
  float a1 = fmaxf(fmaxf(xrow[tsrc[j0 + 1]] * twa[j0 + 1], 0.0f) * twb[j0 + 1], 0.0f);
  unsigned int packed = (unsigned int)f2bf(a0) | ((unsigned int)f2bf(a1) << 16);
  ((unsigned int*)(hr + F0v))[tid] = packed;
}

// ---------------------------------------------------------------------------
// Kernel 2: W f32 -> bf16 (8 elems/thread)
// ---------------------------------------------------------------------------
__global__ __launch_bounds__(256) void convert_kernel(
    const float* __restrict__ Wd, unsigned short* __restrict__ Wb) {
  int gid = blockIdx.x * 256 + threadIdx.x;
  const float4* src = (const float4*)Wd;
  float4 a = src[gid * 2];
  float4 b = src[gid * 2 + 1];
  union { unsigned short us[8]; uint4 u4; } pk;
  pk.us[0] = f2bf(a.x); pk.us[1] = f2bf(a.y);
  pk.us[2] = f2bf(a.z); pk.us[3] = f2bf(a.w);
  pk.us[4] = f2bf(b.x); pk.us[5] = f2bf(b.y);
  pk.us[6] = f2bf(b.z); pk.us[7] = f2bf(b.w);
  ((uint4*)Wb)[gid] = pk.u4;
}

// ---------------------------------------------------------------------------
// Kernel 3: C = h @ W^T + bias.  128x128 tile, BK=64, dbuf LDS, 256 threads
// (4 waves), wave-tile 64x64 = 2x2 of mfma_f32_32x32x16_bf16.
// Rationale (round-4 model): round-3 was LDS-BW-bound (12 ds_read_b128 per
// 16 small MFMAs). 32x32x16 MFMA amortizes 2 KB of fragments over 32K FLOP
// (vs 16K), cutting LDS read cycles per block-iter 1152 -> 770 vs MFMA 516.
// XOR swizzle seg^(row&7) on 16B segs: even bank spread, 0 conflicts (R3).
// ---------------------------------------------------------------------------
#define BM 128
#define BN 128
#define BK 64

__global__ __launch_bounds__(256) void gemm_bt_kernel(
    const unsigned short* __restrict__ A,
    const unsigned short* __restrict__ Bw,
    const float* __restrict__ bias,
    float* __restrict__ C) {
  __shared__ unsigned short As[2][BM * BK];   // 2 x 16 KB
  __shared__ unsigned short Bs[2][BN * BK];   // 2 x 16 KB
  const int tid = threadIdx.x;
  const int wave = tid >> 6;      // 0..3
  const int lane = tid & 63;

  // XCD swizzle: grid (8, 64); id%8 = XCD. XCD k owns M-tiles [8k,8k+8).
  const int id = blockIdx.y * 8 + blockIdx.x;
  const int ty = (id & 7) * 8 + ((id >> 3) & 7);   // M-tile 0..63
  const int tx = id >> 6;                          // N-tile 0..7
  const int m0 = ty * BM;
  const int n0 = tx * BN;
  const int wm = wave >> 1;       // 0..1  (64-row half of M)
  const int wn = wave & 1;        // 0..1  (64-col half of N)
  const int l31 = lane & 31;
  const int lh = lane >> 5;       // 0..1
  const int r7 = l31 & 7;

  // Staging: chunk = 8 rows x 64 cols (1 KiB); A,B each 16 chunks; wave w
  // stages chunks {4w..4w+3} of both. Lane L: row L/8, stored seg L%8,
  // sourcing global seg (L%8)^((L/8)&7)  [XOR swizzle].
  const int lrow = lane >> 3;                 // 0..7 within chunk
  const int gseg = ((lane & 7) ^ (lrow & 7));
  const unsigned short* gA = A + (size_t)(m0 + wave * 32 + lrow) * F2v + gseg * 8;
  const unsigned short* gB = Bw + (size_t)(n0 + wave * 32 + lrow) * F2v + gseg * 8;
  const int lbase = wave * 2048;              // 4 chunks x 512 elems

  floatx16 acc[2][2];
#pragma unroll
  for (int i = 0; i < 2; ++i)
#pragma unroll
    for (int j = 0; j < 2; ++j)
#pragma unroll
      for (int r = 0; r < 16; ++r) acc[i][j][r] = 0.f;

  // prologue: stage k-block 0 into buffer 0
#pragma unroll
  for (int c = 0; c < 4; ++c) {
    async_ld16(gA + (size_t)c * 8 * F2v, &As[0][lbase + c * 512]);
    async_ld16(gB + (size_t)c * 8 * F2v, &Bs[0][lbase + c * 512]);
  }

  for (int k0 = 0; k0 < F2v; k0 += BK) {
    const int pb = (k0 >> 6) & 1;
    __syncthreads();   // drains this buffer's loads; frees other buffer
    if (k0 + BK < F2v) {
      const int nb = pb ^ 1;
#pragma unroll
      for (int c = 0; c < 4; ++c) {
        async_ld16(gA + (k0 + BK) + (size_t)c * 8 * F2v, &As[nb][lbase + c * 512]);
        async_ld16(gB + (k0 + BK) + (size_t)c * 8 * F2v, &Bs[nb][lbase + c * 512]);
      }
    }

    // 4 k-steps of 16; A frag: lane holds A[wm*64+mi*32+l31][t*16+lh*8 .. +8]
    // stored seg = (2t+lh) ^ (row&7)
#pragma unroll
    for (int t = 0; t < 4; ++t) {
      const int sseg = (((2 * t + lh) ^ r7) * 8);
      bf16x8 af[2], bfr[2];
#pragma unroll
      for (int mi = 0; mi < 2; ++mi) {
        int row = wm * 64 + mi * 32 + l31;
        af[mi] = *(const bf16x8*)&As[pb][row * BK + sseg];
      }
#pragma unroll
      for (int ni = 0; ni < 2; ++ni) {
        int row = wn * 64 + ni * 32 + l31;
        bfr[ni] = *(const bf16x8*)&Bs[pb][row * BK + sseg];
      }
#pragma unroll
      for (int mi = 0; mi < 2; ++mi)
#pragma unroll
        for (int ni = 0; ni < 2; ++ni)
          acc[mi][ni] = __builtin_amdgcn_mfma_f32_32x32x16_bf16(
              af[mi], bfr[ni], acc[mi][ni], 0, 0, 0);
    }
  }

  // Epilogue: 32x32 C/D layout col = lane&31, row = (r&3)+8*(r>>2)+4*lh
  // (m74/m101 verified)
#pragma unroll
  for (int ni = 0; ni < 2; ++ni) {
    int col = n0 + wn * 64 + ni * 32 + l31;
    float bc = bias[col];
#pragma unroll
    for (int mi = 0; mi < 2; ++mi) {
      int rbase = m0 + wm * 64 + mi * 32 + 4 * lh;
#pragma unroll
      for (int r = 0; r < 16; ++r) {
        int row = rbase + (r & 3) + 8 * (r >> 2);
        C[(size_t)row * ODIM + col] = acc[mi][ni][r] + bc;
      }
    }
  }
}

// ---------------------------------------------------------------------------
extern "C" void kernel_launch(void* const* d_in, const int* in_sizes, int n_in,
                              void* d_out, int out_size, void* d_ws, size_t ws_size,
                              hipStream_t stream) {
  const float* x    = (const float*)d_in[0];
  const float* e1w  = (const float*)d_in[1];
  const float* e2w  = (const float*)d_in[2];
  const float* wv   = (const float*)d_in[3];
  const float* bv   = (const float*)d_in[4];
  const int*   e1p  = (const int*)d_in[5];
  const int*   e2p  = (const int*)d_in[6];
  const int*   wr   = (const int*)d_in[7];
  const int*   wc   = (const int*)d_in[8];
  const int*   bidx = (const int*)d_in[9];
  float* out = (float*)d_out;

  // Workspace carve (total ~57.7 MB)
  char* ws = (char*)d_ws;
  const size_t h_bytes  = (size_t)BROWS * F2v * 2;        // 41,943,040
  const size_t wd_bytes = (size_t)ODIM * F2v * 4;         // 10,485,760
  const size_t b_bytes  = (size_t)ODIM * 4;               // 4,096
  unsigned short* h   = (unsigned short*)ws;
  float* Wd           = (float*)(ws + h_bytes);
  float* bias         = (float*)(ws + h_bytes + wd_bytes);
  unsigned short* Wb  = (unsigned short*)(ws + h_bytes + wd_bytes + b_bytes);

  hipMemsetAsync(Wd, 0, wd_bytes + b_bytes, stream);
  fused_pre_kernel<<<BROWS + NNZv / 256, 256, 0, stream>>>(
      x, e1w, e2w, e1p, e2p, h, wr, wc, wv, bidx, bv, Wd, bias);
  convert_kernel<<<(ODIM * F2v / 8) / 256, 256, 0, stream>>>(Wd, Wb);
  gemm_bt_kernel<<<dim3(ODIM / BN, BROWS / BM), 256, 0, stream>>>(h, Wb, bias, out);
}

// Round 6
// 184.217 us; speedup vs baseline: 1.1799x; 1.0357x over previous
//
#include <hip/hip_runtime.h>
#include <hip/hip_bf16.h>
#include <cstdint>
#include <cstddef>

// Problem constants (from reference)
#define F0v   2048
#define F1v   2304
#define F2v   2560
#define E1v   256
#define E2v   256
#define BROWS 8192
#define ODIM  1024
#define NNZv  262144
#define NBv   1024

typedef __bf16 bf16x8 __attribute__((ext_vector_type(8)));
typedef float floatx4 __attribute__((ext_vector_type(4)));

__device__ __forceinline__ unsigned short f2bf(float f) {
  unsigned int u = __float_as_uint(f);
  u += 0x7FFFu + ((u >> 16) & 1u);   // round-to-nearest-even
  return (unsigned short)(u >> 16);
}

__device__ __forceinline__ void async_ld16(const void* g, void* l) {
  __builtin_amdgcn_global_load_lds(
      (const __attribute__((address_space(1))) unsigned int*)g,
      (__attribute__((address_space(3))) unsigned int*)l, 16, 0, 0);
}

// ---------------------------------------------------------------------------
// Kernel 1 (fused): blocks [0,8192) build h rows (one barrier, closed-form
// two-hop tails); blocks [8192,9216) do the COO scatter-add.
// ---------------------------------------------------------------------------
__global__ __launch_bounds__(256) void fused_pre_kernel(
    const float* __restrict__ x, const float* __restrict__ e1w,
    const float* __restrict__ e2w, const int* __restrict__ e1p,
    const int* __restrict__ e2p, unsigned short* __restrict__ h,
    const int* __restrict__ wr, const int* __restrict__ wc,
    const float* __restrict__ wv, const int* __restrict__ bidx,
    const float* __restrict__ bv, float* __restrict__ Wd,
    float* __restrict__ bias) {
  __shared__ float xrow[F0v];
  __shared__ int   tsrc[E1v + E2v];
  __shared__ float twa[E1v + E2v];
  __shared__ float twb[E1v + E2v];
  const int tid = threadIdx.x;

  if (blockIdx.x >= BROWS) {
    int gid = (blockIdx.x - BROWS) * 256 + tid;
    if (gid < NNZv)
      atomicAdd(&Wd[(size_t)wr[gid] * F2v + wc[gid]], wv[gid]);
    if (gid < NBv)
      atomicAdd(&bias[bidx[gid]], bv[gid]);
    return;
  }

  const int b = blockIdx.x;
  const float* xr = x + (size_t)b * F0v;
  unsigned short* hr = h + (size_t)b * F2v;

  {
    tsrc[tid] = e1p[tid]; twa[tid] = e1w[tid]; twb[tid] = 1.0f;
    int p2 = e2p[tid]; float w2 = e2w[tid];
    if (p2 < F0v) {
      tsrc[E1v + tid] = p2;  twa[E1v + tid] = w2;  twb[E1v + tid] = 1.0f;
    } else {
      int q = p2 - F0v;
      tsrc[E1v + tid] = e1p[q]; twa[E1v + tid] = e1w[q]; twb[E1v + tid] = w2;
    }
  }

  float4 v0 = ((const float4*)xr)[tid * 2];
  float4 v1 = ((const float4*)xr)[tid * 2 + 1];
  ((float4*)xrow)[tid * 2] = v0;
  ((float4*)xrow)[tid * 2 + 1] = v1;
  union { unsigned short us[8]; uint4 u4; } pk;
  pk.us[0] = f2bf(v0.x); pk.us[1] = f2bf(v0.y);
  pk.us[2] = f2bf(v0.z); pk.us[3] = f2bf(v0.w);
  pk.us[4] = f2bf(v1.x); pk.us[5] = f2bf(v1.y);
  pk.us[6] = f2bf(v1.z); pk.us[7] = f2bf(v1.w);
  ((uint4*)hr)[tid] = pk.u4;
  __syncthreads();

  int j0 = tid * 2;
  float a0 = fmaxf(fmaxf(xrow[tsrc[j0]] * twa[j0], 0.0f) * twb[j0], 0.0f);
  float a1 = fmaxf(fmaxf(xrow[tsrc[j0 + 1]] * twa[j0 + 1], 0.0f) * twb[j0 + 1], 0.0f);
  unsigned int packed = (unsigned int)f2bf(a0) | ((unsigned int)f2bf(a1) << 16);
  ((unsigned int*)(hr + F0v))[tid] = packed;
}

// ---------------------------------------------------------------------------
// Kernel 2: W f32 -> bf16 (8 elems/thread)
// ---------------------------------------------------------------------------
__global__ __launch_bounds__(256) void convert_kernel(
    const float* __restrict__ Wd, unsigned short* __restrict__ Wb) {
  int gid = blockIdx.x * 256 + threadIdx.x;
  const float4* src = (const float4*)Wd;
  float4 a = src[gid * 2];
  float4 b = src[gid * 2 + 1];
  union { unsigned short us[8]; uint4 u4; } pk;
  pk.us[0] = f2bf(a.x); pk.us[1] = f2bf(a.y);
  pk.us[2] = f2bf(a.z); pk.us[3] = f2bf(a.w);
  pk.us[4] = f2bf(b.x); pk.us[5] = f2bf(b.y);
  pk.us[6] = f2bf(b.z); pk.us[7] = f2bf(b.w);
  ((uint4*)Wb)[gid] = pk.u4;
}

// ---------------------------------------------------------------------------
// Kernel 3: C = h @ W^T + bias.  128x128 tile, BK=64 dbuf, 256 threads
// (4 waves, 2x2), wave-tile 64x64 = acc[4][4] of 16x16x32 bf16 MFMA.
// Empirical conflict law (R1/R2/R5 = 4 extra cyc/read; R3/R4 = 0): fragment
// reads must keep the R3 pattern class — 16-row span (r16) with quad in the
// seg XOR: seg = (kk*4+quad)^(r16&7). 8 reads serve 16 MFMAs per kk (same
// FLOP/byte as the 32x32 path) without its 32-row-span conflict penalty.
// LDS 64 KB -> 2 blocks/CU; grid 512 -> barrier phases interleave.
// ---------------------------------------------------------------------------
#define BM 128
#define BN 128
#define BK 64

__global__ __launch_bounds__(256) void gemm_bt_kernel(
    const unsigned short* __restrict__ A,
    const unsigned short* __restrict__ Bw,
    const float* __restrict__ bias,
    float* __restrict__ C) {
  __shared__ unsigned short As[2][BM * BK];   // 2 x 16 KB
  __shared__ unsigned short Bs[2][BN * BK];   // 2 x 16 KB
  const int tid = threadIdx.x;
  const int wave = tid >> 6;      // 0..3
  const int lane = tid & 63;

  // XCD swizzle: grid (8, 64); id%8 = XCD. XCD k owns M-tiles [8k,8k+8).
  const int id = blockIdx.y * 8 + blockIdx.x;
  const int ty = (id & 7) * 8 + ((id >> 3) & 7);   // M-tile 0..63
  const int tx = id >> 6;                          // N-tile 0..7
  const int m0 = ty * BM;
  const int n0 = tx * BN;
  const int wm = wave >> 1;       // 0..1  (64-row half of M)
  const int wn = wave & 1;        // 0..1  (64-col half of N)
  const int quad = lane >> 4;     // 0..3
  const int r16 = lane & 15;
  const int r7 = r16 & 7;

  // Staging: chunk = 8 rows x 64 cols (1 KiB); A,B each 16 chunks; wave w
  // stages chunks {4w..4w+3} of both. Lane L: row L/8, stored seg L%8,
  // sourcing global seg (L%8)^((L/8)&7)  [XOR swizzle, verified R3/R5].
  const int lrow = lane >> 3;                 // 0..7 within chunk
  const int gseg = ((lane & 7) ^ (lrow & 7));
  const unsigned short* gA = A + (size_t)(m0 + wave * 32 + lrow) * F2v + gseg * 8;
  const unsigned short* gB = Bw + (size_t)(n0 + wave * 32 + lrow) * F2v + gseg * 8;
  const int lbase = wave * 2048;              // 4 chunks x 512 elems

  floatx4 acc[4][4];
  floatx4 zz = {0.f, 0.f, 0.f, 0.f};
#pragma unroll
  for (int i = 0; i < 4; ++i)
#pragma unroll
    for (int j = 0; j < 4; ++j) acc[i][j] = zz;

  // prologue: stage k-block 0 into buffer 0
#pragma unroll
  for (int c = 0; c < 4; ++c) {
    async_ld16(gA + (size_t)c * 8 * F2v, &As[0][lbase + c * 512]);
    async_ld16(gB + (size_t)c * 8 * F2v, &Bs[0][lbase + c * 512]);
  }

  for (int k0 = 0; k0 < F2v; k0 += BK) {
    const int pb = (k0 >> 6) & 1;
    __syncthreads();   // drains this buffer's loads; frees other buffer
    if (k0 + BK < F2v) {
      const int nb = pb ^ 1;
#pragma unroll
      for (int c = 0; c < 4; ++c) {
        async_ld16(gA + (k0 + BK) + (size_t)c * 8 * F2v, &As[nb][lbase + c * 512]);
        async_ld16(gB + (k0 + BK) + (size_t)c * 8 * F2v, &Bs[nb][lbase + c * 512]);
      }
    }

    // 2 k-steps of 32; fragment (row, k-seg kk*4+quad) stored at
    // seg = (kk*4+quad)^(row&7); row&7 == r16&7 (bases are x16 multiples).
#pragma unroll
    for (int kk = 0; kk < 2; ++kk) {
      const int sseg = (((kk * 4 + quad) ^ r7) * 8);
      bf16x8 af[4], bfr[4];
#pragma unroll
      for (int mi = 0; mi < 4; ++mi) {
        int row = wm * 64 + mi * 16 + r16;
        af[mi] = *(const bf16x8*)&As[pb][row * BK + sseg];
      }
#pragma unroll
      for (int ni = 0; ni < 4; ++ni) {
        int row = wn * 64 + ni * 16 + r16;
        bfr[ni] = *(const bf16x8*)&Bs[pb][row * BK + sseg];
      }
#pragma unroll
      for (int mi = 0; mi < 4; ++mi)
#pragma unroll
        for (int ni = 0; ni < 4; ++ni)
          acc[mi][ni] = __builtin_amdgcn_mfma_f32_16x16x32_bf16(
              af[mi], bfr[ni], acc[mi][ni], 0, 0, 0);
    }
  }

  // Epilogue: C/D layout col = lane&15, row = quad*4 + reg (m89/m91 verified)
#pragma unroll
  for (int ni = 0; ni < 4; ++ni) {
    int col = n0 + wn * 64 + ni * 16 + r16;
    float bc = bias[col];
#pragma unroll
    for (int mi = 0; mi < 4; ++mi) {
      int row = m0 + wm * 64 + mi * 16 + quad * 4;
#pragma unroll
      for (int rg = 0; rg < 4; ++rg)
        C[(size_t)(row + rg) * ODIM + col] = acc[mi][ni][rg] + bc;
    }
  }
}

// ---------------------------------------------------------------------------
extern "C" void kernel_launch(void* const* d_in, const int* in_sizes, int n_in,
                              void* d_out, int out_size, void* d_ws, size_t ws_size,
                              hipStream_t stream) {
  const float* x    = (const float*)d_in[0];
  const float* e1w  = (const float*)d_in[1];
  const float* e2w  = (const float*)d_in[2];
  const float* wv   = (const float*)d_in[3];
  const float* bv   = (const float*)d_in[4];
  const int*   e1p  = (const int*)d_in[5];
  const int*   e2p  = (const int*)d_in[6];
  const int*   wr   = (const int*)d_in[7];
  const int*   wc   = (const int*)d_in[8];
  const int*   bidx = (const int*)d_in[9];
  float* out = (float*)d_out;

  // Workspace carve (total ~57.7 MB)
  char* ws = (char*)d_ws;
  const size_t h_bytes  = (size_t)BROWS * F2v * 2;        // 41,943,040
  const size_t wd_bytes = (size_t)ODIM * F2v * 4;         // 10,485,760
  const size_t b_bytes  = (size_t)ODIM * 4;               // 4,096
  unsigned short* h   = (unsigned short*)ws;
  float* Wd           = (float*)(ws + h_bytes);
  float* bias         = (float*)(ws + h_bytes + wd_bytes);
  unsigned short* Wb  = (unsigned short*)(ws + h_bytes + wd_bytes + b_bytes);

  hipMemsetAsync(Wd, 0, wd_bytes + b_bytes, stream);
  fused_pre_kernel<<<BROWS + NNZv / 256, 256, 0, stream>>>(
      x, e1w, e2w, e1p, e2p, h, wr, wc, wv, bidx, bv, Wd, bias);
  convert_kernel<<<(ODIM * F2v / 8) / 256, 256, 0, stream>>>(Wd, Wb);
  gemm_bt_kernel<<<dim3(ODIM / BN, BROWS / BM), 256, 0, stream>>>(h, Wb, bias, out);
}